// Round 2
// baseline (315.005 us; speedup 1.0000x reference)
//
#include <hip/hip_runtime.h>

// ---------------------------------------------------------------------------
// ChemConv, reformulated:
//   out[a,o] = sum_{n,f} conn[a,n,f] * W[n*12+f, o] + sum_{f,c} bond[a,f,c]*bf[o,f,c+1]
//   W[n*12+f, o] = bf[o,f,0] * sum_i pf[o,f,i] * x[n,i]
//
// K1 (compute_w):  W (24576 x 64) computed and stored as bf16 hi/lo, o-major.
// K2 (main_gemm):  M=2048,N=64,K=24576 GEMM. conn (f32, 201 MB, read once ->
//                  memory-bound floor ~32us) split on the fly into bf16 hi/lo;
//                  3 MFMA products (hh + hl + lh) give ~2^-18 relative error.
//                  32-way K-split for occupancy (1024 blocks, 4/CU).
// K3 (reduce):     sum 32 partials + fused bond term.
//
// ws layout: [WT_hi 3.0MB][WT_lo 3.0MB][partials 16MB]  (needs ~22 MB)
// ---------------------------------------------------------------------------

#define NATOM 2048
#define IN_D 64
#define OUT_D 64
#define FLEN 12
#define KTOT (NATOM * FLEN)        // 24576
#define KSPLIT 32
#define KCHUNK (KTOT / KSPLIT)     // 768
#define BM 64
#define KS 64                      // k staged per LDS iteration
#define NITER (KCHUNK / KS)        // 12
#define LDSW 72                    // ushort stride per LDS row (144 B, 16B-aligned frags)

typedef __attribute__((ext_vector_type(8))) short short8;   // MFMA bf16 A/B frag (guide §3)
typedef __attribute__((ext_vector_type(4))) float f32x4;    // MFMA C/D frag
typedef __attribute__((ext_vector_type(8))) unsigned short u16x8;
typedef __attribute__((ext_vector_type(4))) unsigned short u16x4;

// Round-to-nearest-even f32 -> bf16 split: x ~= hi + lo with |x-hi-lo| <~ 2^-18 |x|
__device__ __forceinline__ void split_bf16(float x, unsigned short& h, unsigned short& l) {
    unsigned int u = __builtin_bit_cast(unsigned int, x);
    unsigned int r = u + 0x7fffu + ((u >> 16) & 1u);
    h = (unsigned short)(r >> 16);
    float hf = __builtin_bit_cast(float, r & 0xffff0000u);
    float res = x - hf;                       // exact (Sterbenz)
    unsigned int u2 = __builtin_bit_cast(unsigned int, res);
    l = (unsigned short)((u2 + 0x7fffu + ((u2 >> 16) & 1u)) >> 16);
}

// ---------------------------------------------------------------------------
// K1: W[o][k=n*12+f] = bf[o,f,0] * sum_i pf[o,f,i]*x[n,i], split hi/lo bf16.
// grid 512 = 16 o-blocks(4 o each) x 32 n-blocks(64 n each); 256 thr.
// ---------------------------------------------------------------------------
__global__ __launch_bounds__(256) void compute_w_kernel(
    const float* __restrict__ x,        // [2048][64]
    const float* __restrict__ pf,       // [64][12][64]
    const float* __restrict__ bf,       // [64][12][3]
    unsigned short* __restrict__ wt_hi, // [64][24576]
    unsigned short* __restrict__ wt_lo)
{
    __shared__ float x_lds[64][66];     // +2 pad: ~conflict-free lane-row reads
    const int t = threadIdx.x;
    const int ob = blockIdx.x & 15;
    const int nb = blockIdx.x >> 4;

    {   // stage 64 x-rows of this n-block
        const int r = t >> 2;
        const int i0 = (t & 3) * 16;
        const float* src = x + (nb * 64 + r) * IN_D + i0;
        #pragma unroll
        for (int j = 0; j < 4; ++j) {
            float4 v = *(const float4*)(src + 4 * j);
            x_lds[r][i0 + 4 * j + 0] = v.x;
            x_lds[r][i0 + 4 * j + 1] = v.y;
            x_lds[r][i0 + 4 * j + 2] = v.z;
            x_lds[r][i0 + 4 * j + 3] = v.w;
        }
    }
    __syncthreads();

    const int l = t & 63;               // n within block (lane)
    const int o = ob * 4 + (t >> 6);    // wave-uniform o -> pf loads broadcast
    const int n = nb * 64 + l;

    float acc[FLEN];
    #pragma unroll
    for (int f = 0; f < FLEN; ++f) acc[f] = 0.f;

    for (int i = 0; i < IN_D; i += 4) {
        float x0 = x_lds[l][i + 0], x1 = x_lds[l][i + 1];
        float x2 = x_lds[l][i + 2], x3 = x_lds[l][i + 3];
        #pragma unroll
        for (int f = 0; f < FLEN; ++f) {
            float4 p = *(const float4*)(pf + (o * FLEN + f) * IN_D + i);
            acc[f] += p.x * x0 + p.y * x1 + p.z * x2 + p.w * x3;
        }
    }

    unsigned short hi[FLEN], lo[FLEN];
    #pragma unroll
    for (int f = 0; f < FLEN; ++f) {
        float wv = acc[f] * bf[(o * FLEN + f) * 3 + 0];
        split_bf16(wv, hi[f], lo[f]);
    }
    unsigned short* dh = wt_hi + o * KTOT + n * FLEN;  // 24B per lane, contiguous per wave
    unsigned short* dl = wt_lo + o * KTOT + n * FLEN;
    #pragma unroll
    for (int q = 0; q < 3; ++q) {
        u16x4 vh = { hi[4*q], hi[4*q+1], hi[4*q+2], hi[4*q+3] };
        u16x4 vl = { lo[4*q], lo[4*q+1], lo[4*q+2], lo[4*q+3] };
        *(u16x4*)(dh + 4 * q) = vh;
        *(u16x4*)(dl + 4 * q) = vl;
    }
}

// ---------------------------------------------------------------------------
// K2: main GEMM. grid 1024 = 32 m-blocks x 32 k-chunks; 256 thr (4 waves).
// Per iter: stage conn[64a][64k] f32 -> split bf16 LDS, W[64o][64k] hi/lo LDS;
// each wave: one 16-row band x 4 n-tiles, 2 k-steps x 3 products of
// v_mfma_f32_16x16x32_bf16. A/B frags use identical lane->k maps so any k-order
// ambiguity cancels. C/D map (verified): col=lane&15, row=(lane>>4)*4+reg.
// ---------------------------------------------------------------------------
__global__ __launch_bounds__(256, 4) void main_gemm_kernel(
    const float* __restrict__ conn,     // [2048][24576]
    const unsigned short* __restrict__ wt_hi,
    const unsigned short* __restrict__ wt_lo,
    float* __restrict__ partials)       // [KSPLIT][2048][64]
{
    __shared__ unsigned short lds[4][BM][LDSW];  // Ah, Al, Bh, Bl  (36,864 B)

    const int t = threadIdx.x;
    const int mblk = blockIdx.x & 31;
    const int kblk = blockIdx.x >> 5;
    const int mBase = mblk * BM;
    const int kBase = kblk * KCHUNK;

    // staging roles
    const int r = t >> 2;               // 0..63: conn row a / W row o
    const int p = t & 3;
    // compute roles
    const int l = t & 63;
    const int w = t >> 6;               // wave -> 16-row band
    const int lr = l & 15;
    const int g = l >> 4;

    f32x4 acc[4];
    #pragma unroll
    for (int nbt = 0; nbt < 4; ++nbt) acc[nbt] = 0.f;

    const float* connRow = conn + (long)(mBase + r) * KTOT + kBase;
    const unsigned short* whRow = wt_hi + r * KTOT + kBase;
    const unsigned short* wlRow = wt_lo + r * KTOT + kBase;

    #pragma unroll 1
    for (int it = 0; it < NITER; ++it) {
        const int kOff = it * KS;
        // ---- stage conn -> Ah/Al (on-the-fly hi/lo split) ----
        #pragma unroll
        for (int j = 0; j < 4; ++j) {
            const int kq = p * 4 + j * 16;
            float4 v = *(const float4*)(connRow + kOff + kq);
            unsigned short h0, h1, h2, h3, l0, l1, l2, l3;
            split_bf16(v.x, h0, l0);
            split_bf16(v.y, h1, l1);
            split_bf16(v.z, h2, l2);
            split_bf16(v.w, h3, l3);
            u16x4 h = { h0, h1, h2, h3 };
            u16x4 lo = { l0, l1, l2, l3 };
            *(u16x4*)&lds[0][r][kq] = h;
            *(u16x4*)&lds[1][r][kq] = lo;
        }
        // ---- stage W -> Bh/Bl (pre-split, L2-resident) ----
        #pragma unroll
        for (int j2 = 0; j2 < 2; ++j2) {
            const int ko = p * 16 + j2 * 8;
            *(u16x8*)&lds[2][r][ko] = *(const u16x8*)(whRow + kOff + ko);
            *(u16x8*)&lds[3][r][ko] = *(const u16x8*)(wlRow + kOff + ko);
        }
        __syncthreads();
        // ---- MFMA ----
        #pragma unroll
        for (int kk = 0; kk < 2; ++kk) {
            const int ke = kk * 32 + g * 8;       // lane's 8 contiguous k (same map A & B)
            short8 ah = *(const short8*)&lds[0][16 * w + lr][ke];
            short8 al = *(const short8*)&lds[1][16 * w + lr][ke];
            #pragma unroll
            for (int nbt = 0; nbt < 4; ++nbt) {
                short8 bh = *(const short8*)&lds[2][16 * nbt + lr][ke];
                short8 bl = *(const short8*)&lds[3][16 * nbt + lr][ke];
                acc[nbt] = __builtin_amdgcn_mfma_f32_16x16x32_bf16(al, bh, acc[nbt], 0, 0, 0);
                acc[nbt] = __builtin_amdgcn_mfma_f32_16x16x32_bf16(ah, bl, acc[nbt], 0, 0, 0);
                acc[nbt] = __builtin_amdgcn_mfma_f32_16x16x32_bf16(ah, bh, acc[nbt], 0, 0, 0);
            }
        }
        __syncthreads();
    }

    // ---- write partial tile ----
    float* dst = partials + (long)kblk * (NATOM * OUT_D);
    #pragma unroll
    for (int nbt = 0; nbt < 4; ++nbt) {
        #pragma unroll
        for (int rr = 0; rr < 4; ++rr) {
            const int a = mBase + 16 * w + g * 4 + rr;   // row=(lane>>4)*4+reg
            const int o = nbt * 16 + lr;                 // col=lane&15
            dst[a * OUT_D + o] = acc[nbt][rr];
        }
    }
}

// ---------------------------------------------------------------------------
// K3: out[a,o] = sum_s partials[s][a][o] + sum_f (bond[a,f,0]*bf[o,f,1]
//                                               + bond[a,f,1]*bf[o,f,2])
// ---------------------------------------------------------------------------
__global__ __launch_bounds__(256) void reduce_kernel(
    const float* __restrict__ partials,
    const float* __restrict__ bond,     // [2048][12][2]
    const float* __restrict__ bf,       // [64][12][3]
    float* __restrict__ out)            // [2048][64]
{
    const int idx = blockIdx.x * 256 + threadIdx.x;
    const int a = idx >> 6;
    const int o = idx & 63;
    float s = 0.f;
    #pragma unroll
    for (int kb = 0; kb < KSPLIT; ++kb)
        s += partials[(long)kb * (NATOM * OUT_D) + idx];
    const float* brow = bond + a * (FLEN * 2);   // wave-uniform -> broadcast
    #pragma unroll
    for (int f = 0; f < FLEN; ++f) {
        s += brow[2 * f + 0] * bf[(o * FLEN + f) * 3 + 1];
        s += brow[2 * f + 1] * bf[(o * FLEN + f) * 3 + 2];
    }
    out[idx] = s;
}

extern "C" void kernel_launch(void* const* d_in, const int* in_sizes, int n_in,
                              void* d_out, int out_size, void* d_ws, size_t ws_size,
                              hipStream_t stream) {
    const float* x    = (const float*)d_in[0];   // node_property  [2048][64]
    const float* conn = (const float*)d_in[1];   // connectivity   [2048][2048][12]
    const float* bond = (const float*)d_in[2];   // bond_property  [2048][12][2]
    const float* pf   = (const float*)d_in[3];   // property_filters [64][12][64]
    const float* bf   = (const float*)d_in[4];   // bond_filters   [64][12][3]
    float* out = (float*)d_out;

    unsigned short* wt_hi = (unsigned short*)d_ws;
    unsigned short* wt_lo = wt_hi + (size_t)OUT_D * KTOT;
    float* partials = (float*)(wt_lo + (size_t)OUT_D * KTOT);
    // ws needed: 2*3,145,728 + 16,777,216 = 23,068,672 B

    compute_w_kernel<<<512, 256, 0, stream>>>(x, pf, bf, wt_hi, wt_lo);
    main_gemm_kernel<<<1024, 256, 0, stream>>>(conn, wt_hi, wt_lo, partials);
    reduce_kernel<<<512, 256, 0, stream>>>(partials, bond, bf, out);
}